// Round 4
// baseline (263.623 us; speedup 1.0000x reference)
//
#include <hip/hip_runtime.h>
#include <stdint.h>

#define EPSV 1e-7f
#define FDIM 512
#define ROWS 32       // rows of x per block, tile resident in LDS (32 KB)
#define NROWS 65536   // 16*4096
#define NBLK (NROWS / ROWS)   // 2048

typedef __bf16 bf16_t;
typedef bf16_t bf16x8 __attribute__((ext_vector_type(8)));
typedef unsigned short ushort8 __attribute__((ext_vector_type(8)));
typedef float f32x4 __attribute__((ext_vector_type(4)));

// RNE float -> bf16
__device__ __forceinline__ unsigned short f2bf(float f) {
  union { float f; unsigned int u; } c; c.f = f;
  unsigned int u = c.u;
  unsigned int r = u + 0x7fffu + ((u >> 16) & 1u);
  return (unsigned short)(r >> 16);
}
__device__ __forceinline__ float bf2f(unsigned short s) {
  union { unsigned int u; float f; } c; c.u = ((unsigned int)s) << 16;
  return c.f;
}

// tanh via hardware exp + rcp; clamped so e^{2x} can't overflow.
__device__ __forceinline__ float fast_tanh(float x) {
  x = fminf(15.0f, fmaxf(-15.0f, x));
  float t = __expf(2.0f * x);
  return 1.0f - 2.0f * __builtin_amdgcn_rcpf(t + 1.0f);
}

// Wt2[k>>5][n][k&31] = bf16(W[k][n]) (k-chunked: a wave's B-fragment load is
// 16 rows x 64B contiguous = fully coalesced). Also zeroes sumE.
__global__ void convert_W(const float* __restrict__ W, unsigned short* __restrict__ Wt2,
                          float* __restrict__ sumE) {
  if (blockIdx.x == 0 && threadIdx.x == 0) *sumE = 0.0f;
  __shared__ unsigned short tile[32][34];
  const int t = threadIdx.x;
  const int tx = t & 31, ty = t >> 5;
  const int bn = blockIdx.x & 15, bk = blockIdx.x >> 4;
  const int k0 = bk * 32, n0 = bn * 32;
#pragma unroll
  for (int i = 0; i < 4; ++i) {
    int r = ty + i * 8;
    tile[r][tx] = f2bf(W[(size_t)(k0 + r) * FDIM + n0 + tx]);
  }
  __syncthreads();
#pragma unroll
  for (int i = 0; i < 4; ++i) {
    int r = ty + i * 8;
    Wt2[(size_t)(k0 >> 5) * (FDIM * 32) + (size_t)(n0 + r) * 32 + tx] = tile[tx][r];
  }
}

// One block = 32 rows x full N=512. 8 waves as 1(M) x 8(N): wave tile 32x64.
// acc = 32 AGPRs -> registers freed for an explicit 2-deep B pipeline:
// bA/bB register sets double-buffer the global->reg W loads so the compiler
// emits counted vmcnt (loads for kc+1 stay in flight across kc's MFMAs).
// A resident in LDS bf16 (swizzled). No barriers in the K loop.
__global__ __launch_bounds__(512, 4) void fused_score_pool(
    const float* __restrict__ x, const unsigned short* __restrict__ Wt2,
    const float* __restrict__ bvec, const float* __restrict__ uvec,
    float* __restrict__ ppool, float* __restrict__ sumE) {
  __shared__ alignas(16) unsigned short sA[ROWS * FDIM];  // 32 KB
  __shared__ float score_s[ROWS];
  __shared__ float e_s[ROWS];

  const int t = threadIdx.x;     // 0..511
  const int lane = t & 63;
  const int w = t >> 6;          // 0..7 : owns cols w*64 .. w*64+63
  const int quad = lane >> 4;
  const int l15 = lane & 15;
  const int m0 = blockIdx.x * ROWS;

  if (t < ROWS) score_s[t] = 0.0f;

  // lane's B base: col = w*64 + ni*16 + l15, k-slot = quad*8 within chunk
  const unsigned short* bp = Wt2 + (size_t)(w * 64 + l15) * 32 + quad * 8;

#define LOADB(dst_, kc_)                                                       \
  do {                                                                         \
    _Pragma("unroll") for (int ni_ = 0; ni_ < 4; ++ni_)                        \
        dst_[ni_] = *(const bf16x8*)(const void*)(                             \
            bp + (size_t)(kc_) * (FDIM * 32) + ni_ * 512);                     \
  } while (0)

  // prologue: first B chunk in flight under stage A
  bf16x8 bA[4], bB[4];
  LOADB(bA, 0);

  // ---- stage A: fp32 x -> bf16 LDS, 16B-block XOR swizzle (proven) ----
#pragma unroll
  for (int p = 0; p < 4; ++p) {
    const int row = p * 8 + w;
    const float* g = x + (size_t)(m0 + row) * FDIM + lane * 8;
    float4 lo = *(const float4*)g;
    float4 hi = *(const float4*)(g + 4);
    ushort8 v;
    v[0] = f2bf(lo.x); v[1] = f2bf(lo.y); v[2] = f2bf(lo.z); v[3] = f2bf(lo.w);
    v[4] = f2bf(hi.x); v[5] = f2bf(hi.y); v[6] = f2bf(hi.z); v[7] = f2bf(hi.w);
    const int jp = lane ^ (row & 7);
    *(ushort8*)(void*)(sA + row * FDIM + jp * 8) = v;
  }
  __syncthreads();   // the ONLY barrier before the epilogue

  f32x4 acc[2][4];
#pragma unroll
  for (int mi = 0; mi < 2; ++mi)
#pragma unroll
    for (int ni = 0; ni < 4; ++ni) acc[mi][ni] = (f32x4){0.f, 0.f, 0.f, 0.f};

#define MFMA_STEP(bcur_, kc_)                                                  \
  do {                                                                         \
    bf16x8 af_[2];                                                             \
    _Pragma("unroll") for (int mi_ = 0; mi_ < 2; ++mi_) {                      \
      const int row_ = mi_ * 16 + l15;                                         \
      const int phys_ = ((kc_) * 4 + quad) ^ (row_ & 7);                       \
      af_[mi_] = *(const bf16x8*)(const void*)(sA + row_ * FDIM + phys_ * 8);  \
    }                                                                          \
    __builtin_amdgcn_s_setprio(1);                                             \
    _Pragma("unroll") for (int mi_ = 0; mi_ < 2; ++mi_)                        \
        _Pragma("unroll") for (int ni_ = 0; ni_ < 4; ++ni_)                    \
            acc[mi_][ni_] = __builtin_amdgcn_mfma_f32_16x16x32_bf16(           \
                af_[mi_], bcur_[ni_], acc[mi_][ni_], 0, 0, 0);                 \
    __builtin_amdgcn_s_setprio(0);                                             \
  } while (0)

  // ---- K loop: 16 chunks, hand-unrolled 2x with register double-buffer ----
#pragma unroll
  for (int kc2 = 0; kc2 < 8; ++kc2) {
    const int kc = kc2 * 2;
    LOADB(bB, kc + 1);            // prefetch: in flight across MFMA(bA)
    MFMA_STEP(bA, kc);
    LOADB(bA, (kc + 2) & 15);     // prefetch (wraps harmlessly on last iter)
    MFMA_STEP(bB, kc + 1);
  }

  // ---- epilogue: sc = sum_n u[n]*tanh(C + b[n]); reduce over 16 col-lanes
  float uu[4], bb[4];
#pragma unroll
  for (int ni = 0; ni < 4; ++ni) {
    const int cl = w * 64 + ni * 16 + l15;
    uu[ni] = uvec[cl];
    bb[ni] = bvec[cl];
  }
#pragma unroll
  for (int mi = 0; mi < 2; ++mi)
#pragma unroll
    for (int r = 0; r < 4; ++r) {
      float v = 0.0f;
#pragma unroll
      for (int ni = 0; ni < 4; ++ni)
        v += uu[ni] * fast_tanh(acc[mi][ni][r] + bb[ni]);
      v += __shfl_xor(v, 1); v += __shfl_xor(v, 2);
      v += __shfl_xor(v, 4); v += __shfl_xor(v, 8);
      if (l15 == 0)
        atomicAdd(&score_s[mi * 16 + quad * 4 + r], v);
    }
  __syncthreads();

  // ---- e = exp(score); block partial of sumE (lanes 0..31 of wave 0) ----
  if (t < ROWS) {
    const float e = __expf(score_s[t]);
    e_s[t] = e;
    float v = e;
    v += __shfl_xor(v, 1);  v += __shfl_xor(v, 2);  v += __shfl_xor(v, 4);
    v += __shfl_xor(v, 8);  v += __shfl_xor(v, 16);
    if (lane == 0) atomicAdd(sumE, v);
  }
  __syncthreads();

  // ---- pooling: one thread per column, sum over the 32 resident rows ----
  {
    const int col = t;                 // 0..511
    const int jblk = col >> 3, jj = col & 7;
    float s = 0.0f;
#pragma unroll 8
    for (int row = 0; row < ROWS; ++row) {
      const int phys = ((jblk ^ (row & 7)) << 3) + jj;
      s += bf2f(sA[row * FDIM + phys]) * e_s[row];
    }
    ppool[(size_t)blockIdx.x * FDIM + col] = s;
  }
}

// out[b,f] = (sum over the 128 row-blocks of batch b) / (sumE + eps)
__global__ __launch_bounds__(256) void finalize(
    const float* __restrict__ ppool, const float* __restrict__ sumE,
    float* __restrict__ out) {
  const int i = blockIdx.x * 256 + threadIdx.x;   // 0..8191
  const int b = i >> 9, f = i & 511;
  const float* p = ppool + (size_t)b * 128 * FDIM + f;
  float s = 0.0f;
#pragma unroll
  for (int c = 0; c < 128; ++c) s += p[(size_t)c * FDIM];
  out[i] = s / (*sumE + EPSV);
}

extern "C" void kernel_launch(void* const* d_in, const int* in_sizes, int n_in,
                              void* d_out, int out_size, void* d_ws, size_t ws_size,
                              hipStream_t stream) {
  (void)in_sizes; (void)n_in; (void)out_size; (void)ws_size;
  const float* x = (const float*)d_in[0];
  const float* W = (const float*)d_in[1];
  const float* b = (const float*)d_in[2];
  const float* u = (const float*)d_in[3];
  float* out = (float*)d_out;

  // ws layout: Wt2 512K | sumE (pad 256) | ppool 4M   (~4.6 MB)
  char* p = (char*)d_ws;
  unsigned short* Wt2 = (unsigned short*)p;  p += (size_t)FDIM * FDIM * 2;
  float* sumE = (float*)p;                   p += 256;
  float* ppool = (float*)p;                  p += (size_t)NBLK * FDIM * 4;

  convert_W<<<dim3(256), dim3(256), 0, stream>>>(W, Wt2, sumE);
  fused_score_pool<<<dim3(NBLK), dim3(512), 0, stream>>>(
      x, Wt2, b, u, ppool, sumE);
  finalize<<<dim3(32), dim3(256), 0, stream>>>(ppool, sumE, out);
}

// Round 5
// 261.907 us; speedup vs baseline: 1.0065x; 1.0065x over previous
//
#include <hip/hip_runtime.h>
#include <stdint.h>

#define EPSV 1e-7f
#define FDIM 512
#define ROWS 32       // rows of x per block, tile resident in LDS (32 KB)
#define NROWS 65536   // 16*4096
#define NBLK (NROWS / ROWS)   // 2048

typedef __bf16 bf16_t;
typedef bf16_t bf16x8 __attribute__((ext_vector_type(8)));
typedef unsigned short ushort8 __attribute__((ext_vector_type(8)));
typedef float f32x4 __attribute__((ext_vector_type(4)));

// RNE float -> bf16
__device__ __forceinline__ unsigned short f2bf(float f) {
  union { float f; unsigned int u; } c; c.f = f;
  unsigned int u = c.u;
  unsigned int r = u + 0x7fffu + ((u >> 16) & 1u);
  return (unsigned short)(r >> 16);
}
__device__ __forceinline__ float bf2f(unsigned short s) {
  union { unsigned int u; float f; } c; c.u = ((unsigned int)s) << 16;
  return c.f;
}

// tanh via hardware exp + rcp; clamped so e^{2x} can't overflow.
__device__ __forceinline__ float fast_tanh(float x) {
  x = fminf(15.0f, fmaxf(-15.0f, x));
  float t = __expf(2.0f * x);
  return 1.0f - 2.0f * __builtin_amdgcn_rcpf(t + 1.0f);
}

// Wt2[k>>5][n][k&31] = bf16(W[k][n]) (k-chunked: a wave's B-fragment load is
// 16 rows x 64B contiguous = fully coalesced). Also zeroes sumE.
__global__ void convert_W(const float* __restrict__ W, unsigned short* __restrict__ Wt2,
                          float* __restrict__ sumE) {
  if (blockIdx.x == 0 && threadIdx.x == 0) *sumE = 0.0f;
  __shared__ unsigned short tile[32][34];
  const int t = threadIdx.x;
  const int tx = t & 31, ty = t >> 5;
  const int bn = blockIdx.x & 15, bk = blockIdx.x >> 4;
  const int k0 = bk * 32, n0 = bn * 32;
#pragma unroll
  for (int i = 0; i < 4; ++i) {
    int r = ty + i * 8;
    tile[r][tx] = f2bf(W[(size_t)(k0 + r) * FDIM + n0 + tx]);
  }
  __syncthreads();
#pragma unroll
  for (int i = 0; i < 4; ++i) {
    int r = ty + i * 8;
    Wt2[(size_t)(k0 >> 5) * (FDIM * 32) + (size_t)(n0 + r) * 32 + tx] = tile[tx][r];
  }
}

// One block = 32 rows x full N=512. 8 waves as 1(M) x 8(N): wave tile 32x64.
// K-loop identical to round 4 (2-deep register-double-buffered B pipeline).
// NEW: (a) all 8 stage-A global loads hoisted & in flight together;
//      (b) staged x kept in registers -> pooling reads REGISTERS, not LDS,
//          reduced across waves via red[] aliased over the dead sA.
__global__ __launch_bounds__(512, 4) void fused_score_pool(
    const float* __restrict__ x, const unsigned short* __restrict__ Wt2,
    const float* __restrict__ bvec, const float* __restrict__ uvec,
    float* __restrict__ ppool, float* __restrict__ sumE) {
  __shared__ alignas(16) unsigned short sA[ROWS * FDIM];  // 32 KB
  __shared__ float score_s[ROWS];
  __shared__ float e_s[ROWS];

  const int t = threadIdx.x;     // 0..511
  const int lane = t & 63;
  const int w = t >> 6;          // 0..7 : owns cols w*64 .. w*64+63
  const int quad = lane >> 4;
  const int l15 = lane & 15;
  const int m0 = blockIdx.x * ROWS;

  if (t < ROWS) score_s[t] = 0.0f;

  // lane's B base: col = w*64 + ni*16 + l15, k-slot = quad*8 within chunk
  const unsigned short* bp = Wt2 + (size_t)(w * 64 + l15) * 32 + quad * 8;

#define LOADB(dst_, kc_)                                                       \
  do {                                                                         \
    _Pragma("unroll") for (int ni_ = 0; ni_ < 4; ++ni_)                        \
        dst_[ni_] = *(const bf16x8*)(const void*)(                             \
            bp + (size_t)(kc_) * (FDIM * 32) + ni_ * 512);                     \
  } while (0)

  bf16x8 bA[4], bB[4];
  LOADB(bA, 0);                 // first B chunk in flight under stage A

  // ---- stage A: hoist ALL 8 x-loads (one round-trip), then convert ----
  float4 L[8];
#pragma unroll
  for (int p = 0; p < 4; ++p) {
    const float* g = x + (size_t)(m0 + p * 8 + w) * FDIM + lane * 8;
    L[2 * p]     = *(const float4*)g;
    L[2 * p + 1] = *(const float4*)(g + 4);
  }
  ushort8 keep[4];              // staged x stays in registers for pooling
#pragma unroll
  for (int p = 0; p < 4; ++p) {
    const int row = p * 8 + w;
    ushort8 v;
    v[0] = f2bf(L[2 * p].x);     v[1] = f2bf(L[2 * p].y);
    v[2] = f2bf(L[2 * p].z);     v[3] = f2bf(L[2 * p].w);
    v[4] = f2bf(L[2 * p + 1].x); v[5] = f2bf(L[2 * p + 1].y);
    v[6] = f2bf(L[2 * p + 1].z); v[7] = f2bf(L[2 * p + 1].w);
    keep[p] = v;
    const int jp = lane ^ (row & 7);
    *(ushort8*)(void*)(sA + row * FDIM + jp * 8) = v;
  }
  __syncthreads();   // the ONLY barrier before the epilogue

  f32x4 acc[2][4];
#pragma unroll
  for (int mi = 0; mi < 2; ++mi)
#pragma unroll
    for (int ni = 0; ni < 4; ++ni) acc[mi][ni] = (f32x4){0.f, 0.f, 0.f, 0.f};

#define MFMA_STEP(bcur_, kc_)                                                  \
  do {                                                                         \
    bf16x8 af_[2];                                                             \
    _Pragma("unroll") for (int mi_ = 0; mi_ < 2; ++mi_) {                      \
      const int row_ = mi_ * 16 + l15;                                         \
      const int phys_ = ((kc_) * 4 + quad) ^ (row_ & 7);                       \
      af_[mi_] = *(const bf16x8*)(const void*)(sA + row_ * FDIM + phys_ * 8);  \
    }                                                                          \
    __builtin_amdgcn_s_setprio(1);                                             \
    _Pragma("unroll") for (int mi_ = 0; mi_ < 2; ++mi_)                        \
        _Pragma("unroll") for (int ni_ = 0; ni_ < 4; ++ni_)                    \
            acc[mi_][ni_] = __builtin_amdgcn_mfma_f32_16x16x32_bf16(           \
                af_[mi_], bcur_[ni_], acc[mi_][ni_], 0, 0, 0);                 \
    __builtin_amdgcn_s_setprio(0);                                             \
  } while (0)

  // ---- K loop: 16 chunks, hand-unrolled 2x with register double-buffer ----
#pragma unroll
  for (int kc2 = 0; kc2 < 8; ++kc2) {
    const int kc = kc2 * 2;
    LOADB(bB, kc + 1);            // prefetch: in flight across MFMA(bA)
    MFMA_STEP(bA, kc);
    LOADB(bA, (kc + 2) & 15);     // prefetch (wraps harmlessly on last iter)
    MFMA_STEP(bB, kc + 1);
  }

  // ---- epilogue: sc = sum_n u[n]*tanh(C + b[n]); reduce over 16 col-lanes
  float uu[4], bb[4];
#pragma unroll
  for (int ni = 0; ni < 4; ++ni) {
    const int cl = w * 64 + ni * 16 + l15;
    uu[ni] = uvec[cl];
    bb[ni] = bvec[cl];
  }
#pragma unroll
  for (int mi = 0; mi < 2; ++mi)
#pragma unroll
    for (int r = 0; r < 4; ++r) {
      float v = 0.0f;
#pragma unroll
      for (int ni = 0; ni < 4; ++ni)
        v += uu[ni] * fast_tanh(acc[mi][ni][r] + bb[ni]);
      v += __shfl_xor(v, 1); v += __shfl_xor(v, 2);
      v += __shfl_xor(v, 4); v += __shfl_xor(v, 8);
      if (l15 == 0)
        atomicAdd(&score_s[mi * 16 + quad * 4 + r], v);
    }
  __syncthreads();

  // ---- e = exp(score); block partial of sumE (lanes 0..31 of wave 0) ----
  if (t < ROWS) {
    const float e = __expf(score_s[t]);
    e_s[t] = e;
    float v = e;
    v += __shfl_xor(v, 1);  v += __shfl_xor(v, 2);  v += __shfl_xor(v, 4);
    v += __shfl_xor(v, 8);  v += __shfl_xor(v, 16);
    if (lane == 0) atomicAdd(sumE, v);
  }
  __syncthreads();

  // ---- pooling from REGISTERS (keep[]), cross-wave reduce via red over sA
  float a[8];
#pragma unroll
  for (int jj = 0; jj < 8; ++jj) a[jj] = 0.0f;
#pragma unroll
  for (int p = 0; p < 4; ++p) {
    const float wg = e_s[p * 8 + w];     // wave-uniform broadcast read
#pragma unroll
    for (int jj = 0; jj < 8; ++jj) a[jj] += bf2f(keep[p][jj]) * wg;
  }
  // sA is dead (last read before the score barrier) -> alias red[8][512] f32
  float* red = (float*)sA;
  *(float4*)&red[w * FDIM + lane * 8]     = (float4){a[0], a[1], a[2], a[3]};
  *(float4*)&red[w * FDIM + lane * 8 + 4] = (float4){a[4], a[5], a[6], a[7]};
  __syncthreads();
  {
    float sv = 0.0f;
#pragma unroll
    for (int g = 0; g < 8; ++g) sv += red[g * FDIM + t];
    ppool[(size_t)blockIdx.x * FDIM + t] = sv;
  }
}

// out[b,f] = (sum over the 128 row-blocks of batch b) / (sumE + eps)
__global__ __launch_bounds__(256) void finalize(
    const float* __restrict__ ppool, const float* __restrict__ sumE,
    float* __restrict__ out) {
  const int i = blockIdx.x * 256 + threadIdx.x;   // 0..8191
  const int b = i >> 9, f = i & 511;
  const float* p = ppool + (size_t)b * 128 * FDIM + f;
  float s = 0.0f;
#pragma unroll
  for (int c = 0; c < 128; ++c) s += p[(size_t)c * FDIM];
  out[i] = s / (*sumE + EPSV);
}

extern "C" void kernel_launch(void* const* d_in, const int* in_sizes, int n_in,
                              void* d_out, int out_size, void* d_ws, size_t ws_size,
                              hipStream_t stream) {
  (void)in_sizes; (void)n_in; (void)out_size; (void)ws_size;
  const float* x = (const float*)d_in[0];
  const float* W = (const float*)d_in[1];
  const float* b = (const float*)d_in[2];
  const float* u = (const float*)d_in[3];
  float* out = (float*)d_out;

  // ws layout: Wt2 512K | sumE (pad 256) | ppool 4M   (~4.6 MB)
  char* p = (char*)d_ws;
  unsigned short* Wt2 = (unsigned short*)p;  p += (size_t)FDIM * FDIM * 2;
  float* sumE = (float*)p;                   p += 256;
  float* ppool = (float*)p;                  p += (size_t)NBLK * FDIM * 4;

  convert_W<<<dim3(256), dim3(256), 0, stream>>>(W, Wt2, sumE);
  fused_score_pool<<<dim3(NBLK), dim3(512), 0, stream>>>(
      x, Wt2, b, u, ppool, sumE);
  finalize<<<dim3(32), dim3(256), 0, stream>>>(ppool, sumE, out);
}